// Round 7
// baseline (148.731 us; speedup 1.0000x reference)
//
#include <hip/hip_runtime.h>

constexpr int N_NODES = 50000;
constexpr int N_EDGES = 800000;
constexpr int D = 64;
constexpr int NB = (N_NODES + 63) / 64;      // 782 buckets of 64 dst nodes
constexpr int BUCKET_CAP = 1792;             // count (<=~1200) + 64*7 pad headroom (x8 padding)
constexpr unsigned ZERO_ROW = 50000u;        // appended all-zero x row (dummy src)
constexpr int CUR_STRIDE = 32;               // u32 units: one 128B line per bucket cursor
constexpr int FUSED_REPS = 3;                // PROBE: repeat k_fused body 3x to expose its
                                             // duration in top-5 (idempotent reps)

typedef __attribute__((ext_vector_type(8))) short short8;
typedef __attribute__((ext_vector_type(4))) float f32x4;

static __device__ inline unsigned short f2bf(float f) {
    unsigned u = __float_as_uint(f);
    unsigned r = (u + 0x7FFFu + ((u >> 16) & 1u)) >> 16;   // RNE
    return (unsigned short)r;
}
static __device__ inline unsigned pack2(float lo, float hi) {
    return (unsigned)f2bf(lo) | ((unsigned)f2bf(hi) << 16);
}
static __device__ inline float bf2f(unsigned short b) {
    return __uint_as_float((unsigned)b << 16);
}

// ---------------------------------------------------------------------------
// 1) merged prep + binning. 256 blocks x 512. (unchanged from round 5)
// ---------------------------------------------------------------------------
constexpr int BIN_BLOCKS = 256;
constexpr int EDGES_PER_BIN_BLOCK = (N_EDGES + BIN_BLOCKS - 1) / BIN_BLOCKS;  // 3125

__global__ __launch_bounds__(512) void k_bin_place(
    const float* __restrict__ x, unsigned short* __restrict__ xb,
    const float* __restrict__ W_msg, const float* __restrict__ W_self,
    unsigned short* __restrict__ B_packed,
    const int* __restrict__ edge_index,
    unsigned* __restrict__ g_cursor, unsigned* __restrict__ bucket_data)
{
    __shared__ unsigned ent_sh[EDGES_PER_BIN_BLOCK];   // 12.5 KB
    __shared__ unsigned lcount[NB];
    __shared__ unsigned lbase[NB];

    int tid = threadIdx.x;

    for (int b = tid; b < NB; b += 512) lcount[b] = 0u;

    // x convert, striped across the whole grid
    int gid = blockIdx.x * 512 + tid;
    for (int t = gid; t < N_NODES * D / 4; t += BIN_BLOCKS * 512) {
        float4 v = ((const float4*)x)[t];
        uint2 p;
        p.x = pack2(v.x, v.y);
        p.y = pack2(v.z, v.w);
        ((uint2*)xb)[t] = p;
    }
    if (blockIdx.x == 0) {
        for (int idx = tid; idx < 64 * 128; idx += 512) {
            int n = idx >> 7;
            int k = idx & 127;
            float v = (k < 64) ? W_self[n * 64 + k] : W_msg[n * 64 + (k - 64)];
            B_packed[idx] = f2bf(v);
        }
    } else if (blockIdx.x == 1) {
        if (tid < 8)   // zero the dummy row: 64 u16 = 8 x uint4
            *(uint4*)&xb[ZERO_ROW * D + tid * 8] = make_uint4(0u, 0u, 0u, 0u);
    }

    int e0 = blockIdx.x * EDGES_PER_BIN_BLOCK;
    int e1 = min(e0 + EDGES_PER_BIN_BLOCK, N_EDGES);
    int ne = e1 - e0;
    __syncthreads();

    // pass 1: read global once, cache in LDS, count buckets
    for (int e = e0 + tid; e < e1; e += 512) {
        int dst = edge_index[N_EDGES + e];
        int src = edge_index[e];
        ent_sh[e - e0] = ((unsigned)src << 16) | (unsigned)dst;
        atomicAdd(&lcount[dst >> 6], 1u);
    }
    __syncthreads();

    for (int b = tid; b < NB; b += 512) {
        unsigned c = lcount[b];
        lbase[b] = c ? ((unsigned)b * BUCKET_CAP + atomicAdd(&g_cursor[b * CUR_STRIDE], c)) : 0u;
    }
    __syncthreads();
    for (int b = tid; b < NB; b += 512) lcount[b] = 0u;
    __syncthreads();

    // pass 2: scatter from LDS
    for (int i = tid; i < ne; i += 512) {
        unsigned ent = ent_sh[i];
        unsigned dst = ent & 0xFFFFu;
        unsigned b   = dst >> 6;
        unsigned off = atomicAdd(&lcount[b], 1u);
        bucket_data[lbase[b] + off] = (ent >> 16) | ((dst & 63u) << 16);
    }
}

// ---------------------------------------------------------------------------
// 2) fused. PROBE build: post-staging body repeated FUSED_REPS times.
//    Each rep fully re-derives cnt/poff/woff/sorted state and rewrites the
//    same output values, so reps are idempotent.
// ---------------------------------------------------------------------------
constexpr int A_STRIDE = 136;   // u16 units; 272B row stride (16B-divisible)

__global__ __launch_bounds__(512) void k_fused(
    const unsigned short* __restrict__ x_bf16,
    const unsigned short* __restrict__ B_packed,
    const float* __restrict__ b_msg, const float* __restrict__ b_self,
    const unsigned* __restrict__ cursor,
    const unsigned* __restrict__ bucket_data,
    float* __restrict__ out)
{
    __shared__ __align__(16) unsigned short A_sh[64 * A_STRIDE];   // 17408 B
    __shared__ __align__(16) unsigned short B_sh[64 * A_STRIDE];   // 17408 B
    __shared__ unsigned short sorted_sh[BUCKET_CAP];               // 3584 B
    __shared__ unsigned cnt_sh[64];      // true counts
    __shared__ unsigned poff_sh[64];     // padded exclusive offsets
    __shared__ unsigned woff_sh[64];     // scatter cursors

    int tid  = threadIdx.x;
    int w    = tid >> 6;       // wave 0..7
    int lane = tid & 63;
    int r0   = blockIdx.x * 64;

    unsigned start = (unsigned)blockIdx.x * BUCKET_CAP;
    unsigned cnt   = cursor[blockIdx.x * CUR_STRIDE];     // true per-bucket edge count

    // register-cache bucket entries (<=4/thread for cnt<=2048)
    unsigned entr[4];
    int ner = 0;
    for (unsigned i = (unsigned)tid; i < cnt && ner < 4; i += 512u)
        entr[ner++] = bucket_data[start + i];

    // stage A x-rows (k<64): 8x 16B chunks per row
    for (int idx = tid; idx < 64 * 8; idx += 512) {
        int row = idx >> 3;
        int c   = idx & 7;
        int g   = r0 + row;
        uint4 v = make_uint4(0u, 0u, 0u, 0u);
        if (g < N_NODES) v = *(const uint4*)&x_bf16[g * D + c * 8];
        *(uint4*)&A_sh[row * A_STRIDE + c * 8] = v;
    }
    // stage B: 16x 16B chunks per row
    for (int idx = tid; idx < 64 * 16; idx += 512) {
        int n = idx >> 4;
        int c = idx & 15;
        uint4 v = *(const uint4*)&B_packed[n * 128 + c * 8];
        *(uint4*)&B_sh[n * A_STRIDE + c * 8] = v;
    }

    // loop-invariant lane decomposition
    int Q = lane >> 4;
    int f = lane & 15;
    int wm   = w & 3;
    int ng   = (w >> 2) * 2;
    int quad = lane >> 4;
    int l15  = lane & 15;

    for (int rep = 0; rep < FUSED_REPS; ++rep) {
        __syncthreads();   // prior rep's readers (gather/out-write) done

        if (tid < 64) cnt_sh[tid] = 0u;
        // prefill sorted list with dummy srcs (covers padding gaps)
        for (int i = tid; i < BUCKET_CAP; i += 512)
            sorted_sh[i] = (unsigned short)ZERO_ROW;
        __syncthreads();

        // count by dst-low (from registers; one global read total)
        #pragma unroll
        for (int q = 0; q < 4; ++q)
            if (q < ner) atomicAdd(&cnt_sh[entr[q] >> 16], 1u);
        for (unsigned i = 4u * 512u + (unsigned)tid; i < cnt; i += 512u)
            atomicAdd(&cnt_sh[bucket_data[start + i] >> 16], 1u);
        __syncthreads();

        // padded (x8) exclusive scan (wave 0)
        if (tid < 64) {
            unsigned c  = cnt_sh[tid];
            unsigned pc = (c + 7u) & ~7u;
            unsigned xsum = pc;
            #pragma unroll
            for (int s = 1; s < 64; s <<= 1) {
                unsigned v = (unsigned)__shfl_up((int)xsum, s);
                if (lane >= s) xsum += v;
            }
            poff_sh[tid] = xsum - pc;
            woff_sh[tid] = xsum - pc;
        }
        __syncthreads();

        // scatter srcs into dst-ordered padded segments (from registers)
        #pragma unroll
        for (int q = 0; q < 4; ++q) {
            if (q < ner) {
                unsigned e = entr[q];
                unsigned slot = atomicAdd(&woff_sh[e >> 16], 1u);
                sorted_sh[slot] = (unsigned short)(e & 0xFFFFu);
            }
        }
        for (unsigned i = 4u * 512u + (unsigned)tid; i < cnt; i += 512u) {
            unsigned e = bucket_data[start + i];
            unsigned slot = atomicAdd(&woff_sh[e >> 16], 1u);
            sorted_sh[slot] = (unsigned short)(e & 0xFFFFu);
        }
        __syncthreads();

        // --- gather: quarter-wave per node; 8 loads in flight per quarter-wave
        #pragma unroll
        for (int pass = 0; pass < 2; ++pass) {
            int lrow = w * 8 + pass * 4 + Q;
            unsigned s0 = poff_sh[lrow];
            unsigned dc = cnt_sh[lrow];
            unsigned pc = (dc + 7u) & ~7u;

            float a0 = 0.f, a1 = 0.f, a2 = 0.f, a3 = 0.f;
            for (unsigned j = 0; j < pc; j += 8u) {
                ushort4 rv[8];
                #pragma unroll
                for (int u = 0; u < 8; ++u) {
                    unsigned src = (unsigned)sorted_sh[s0 + j + u];
                    rv[u] = *(const ushort4*)&x_bf16[(src << 6) + 4u * (unsigned)f];
                }
                #pragma unroll
                for (int u = 0; u < 8; ++u) {
                    a0 += bf2f(rv[u].x); a1 += bf2f(rv[u].y);
                    a2 += bf2f(rv[u].z); a3 += bf2f(rv[u].w);
                }
            }
            float inv = dc ? 1.0f / (float)dc : 0.0f;
            uint2 p;
            p.x = pack2(a0 * inv, a1 * inv);
            p.y = pack2(a2 * inv, a3 * inv);
            *(uint2*)&A_sh[lrow * A_STRIDE + 64 + 4 * f] = p;
        }
        __syncthreads();

        // MFMA: wave w -> m-rows 16*(w&3), n-tiles {2*(w>>2), 2*(w>>2)+1}
        f32x4 accr[2] = {{0.f,0.f,0.f,0.f},{0.f,0.f,0.f,0.f}};

        #pragma unroll
        for (int k0 = 0; k0 < 128; k0 += 32) {
            short8 a = *(const short8*)&A_sh[(16 * wm + l15) * A_STRIDE + k0 + quad * 8];
            #pragma unroll
            for (int t = 0; t < 2; ++t) {
                short8 b = *(const short8*)&B_sh[(16 * (ng + t) + l15) * A_STRIDE + k0 + quad * 8];
                accr[t] = __builtin_amdgcn_mfma_f32_16x16x32_bf16(a, b, accr[t], 0, 0, 0);
            }
        }

        #pragma unroll
        for (int t = 0; t < 2; ++t) {
            int col = (ng + t) * 16 + l15;
            float bs = b_self[col];
            float bm = b_msg[col];
            #pragma unroll
            for (int r = 0; r < 4; ++r) {
                int lrow = 16 * wm + quad * 4 + r;
                int grow = r0 + lrow;
                if (grow < N_NODES) {
                    float vv = accr[t][r] + bs + (cnt_sh[lrow] > 0u ? bm : 0.0f);
                    out[grow * D + col] = vv;
                }
            }
        }
    }
}

// ---------------------------------------------------------------------------
extern "C" void kernel_launch(void* const* d_in, const int* in_sizes, int n_in,
                              void* d_out, int out_size, void* d_ws, size_t ws_size,
                              hipStream_t stream) {
    const float* x      = (const float*)d_in[0];
    const int*   edges  = (const int*)  d_in[1];
    const float* W_msg  = (const float*)d_in[2];
    const float* b_msg  = (const float*)d_in[3];
    const float* W_self = (const float*)d_in[4];
    const float* b_self = (const float*)d_in[5];
    float*       out    = (float*)d_out;

    // workspace layout (bytes), total ~12.3 MB
    char* ws = (char*)d_ws;
    unsigned*       cursor      = (unsigned*)(ws + 0);             // NB line-padded u32 cursors (128B each)
    unsigned short* B_packed    = (unsigned short*)(ws + 102400);  // 16 KB
    unsigned*       bucket_data = (unsigned*)(ws + 118784);        // 782*1792*4 = 5,605,376 B
    unsigned short* x_bf16      = (unsigned short*)(ws + 118784 + (size_t)NB * BUCKET_CAP * 4);
                                                                   // 50001 rows x 128 B

    hipMemsetAsync(cursor, 0, (size_t)NB * CUR_STRIDE * sizeof(unsigned), stream);  // 100 KB

    k_bin_place<<<BIN_BLOCKS, 512, 0, stream>>>(x, x_bf16, W_msg, W_self,
                                                B_packed, edges, cursor, bucket_data);
    k_fused<<<NB, 512, 0, stream>>>(x_bf16, B_packed, b_msg, b_self,
                                    cursor, bucket_data, out);
}

// Round 8
// 112.321 us; speedup vs baseline: 1.3242x; 1.3242x over previous
//
#include <hip/hip_runtime.h>

constexpr int N_NODES = 50000;
constexpr int N_EDGES = 800000;
constexpr int D = 64;
constexpr int NB = (N_NODES + 63) / 64;      // 782 buckets of 64 dst nodes
constexpr int BUCKET_CAP = 1792;             // padded-sorted capacity in k_fused LDS
constexpr unsigned ZERO_ROW = 50000u;        // appended all-zero x row (dummy src)

constexpr int BIN_BLOCKS = 256;
constexpr int EPB = (N_EDGES + BIN_BLOCKS - 1) / BIN_BLOCKS;   // 3125 edges/bin-block
constexpr int SEG_STRIDE = 3136;             // u32 per bin-block edge segment (3125 pad)
constexpr int CNT_STRIDE = 784;              // u32 per bin-block row of off|cnt

typedef __attribute__((ext_vector_type(8))) short short8;
typedef __attribute__((ext_vector_type(4))) float f32x4;

static __device__ inline unsigned short f2bf(float f) {
    unsigned u = __float_as_uint(f);
    unsigned r = (u + 0x7FFFu + ((u >> 16) & 1u)) >> 16;   // RNE
    return (unsigned short)r;
}
static __device__ inline unsigned pack2(float lo, float hi) {
    return (unsigned)f2bf(lo) | ((unsigned)f2bf(hi) << 16);
}
static __device__ inline float bf2f(unsigned short b) {
    return __uint_as_float((unsigned)b << 16);
}

// ---------------------------------------------------------------------------
// 1) prep + LOCAL bin-sort. 256 blocks x 512.
//    All global writes are block-private and coalesced:
//      edge_sorted[blk]: 3125 entries locally sorted by dst-bucket
//      cnt2off[blk][b] = local_off | (local_cnt << 16)
//    No global cursors, no cross-block scattered stores, no memset.
// ---------------------------------------------------------------------------
__global__ __launch_bounds__(512) void k_bin_place(
    const float* __restrict__ x, unsigned short* __restrict__ xb,
    const float* __restrict__ W_msg, const float* __restrict__ W_self,
    unsigned short* __restrict__ B_packed,
    const int* __restrict__ edge_index,
    unsigned* __restrict__ cnt2off, unsigned* __restrict__ edge_sorted)
{
    __shared__ unsigned ent_sh[EPB];        // 12.5 KB
    __shared__ unsigned sort_sh[SEG_STRIDE];// 12.5 KB
    __shared__ unsigned lcount[NB];         // 3.1 KB
    __shared__ unsigned loff[NB + 2];       // 3.1 KB (exclusive offsets / cursors)
    __shared__ unsigned wsum[8];

    int tid  = threadIdx.x;
    int w    = tid >> 6;
    int lane = tid & 63;
    int blk  = blockIdx.x;

    for (int b = tid; b < NB; b += 512) lcount[b] = 0u;

    // x convert, striped across the whole grid
    int gid = blk * 512 + tid;
    for (int t = gid; t < N_NODES * D / 4; t += BIN_BLOCKS * 512) {
        float4 v = ((const float4*)x)[t];
        uint2 p;
        p.x = pack2(v.x, v.y);
        p.y = pack2(v.z, v.w);
        ((uint2*)xb)[t] = p;
    }
    if (blk == 0) {
        for (int idx = tid; idx < 64 * 128; idx += 512) {
            int n = idx >> 7;
            int k = idx & 127;
            float v = (k < 64) ? W_self[n * 64 + k] : W_msg[n * 64 + (k - 64)];
            B_packed[idx] = f2bf(v);
        }
    } else if (blk == 1) {
        if (tid < 8)   // zero the dummy row: 64 u16 = 8 x uint4
            *(uint4*)&xb[ZERO_ROW * D + tid * 8] = make_uint4(0u, 0u, 0u, 0u);
    }

    int e0 = blk * EPB;
    int e1 = min(e0 + EPB, N_EDGES);
    int ne = e1 - e0;
    __syncthreads();

    // pass 1: read edges once, cache in LDS, histogram by bucket
    for (int e = e0 + tid; e < e1; e += 512) {
        int dst = edge_index[N_EDGES + e];
        int src = edge_index[e];
        ent_sh[e - e0] = ((unsigned)src << 16) | (unsigned)dst;
        atomicAdd(&lcount[dst >> 6], 1u);
    }
    __syncthreads();

    // block-wide exclusive scan of lcount[0..NB) (2 elements per thread)
    {
        int i0 = 2 * tid, i1 = 2 * tid + 1;
        unsigned v0 = (i0 < NB) ? lcount[i0] : 0u;
        unsigned v1 = (i1 < NB) ? lcount[i1] : 0u;
        unsigned s  = v0 + v1;
        unsigned xinc = s;
        #pragma unroll
        for (int d = 1; d < 64; d <<= 1) {
            unsigned t = (unsigned)__shfl_up((int)xinc, d);
            if (lane >= d) xinc += t;
        }
        if (lane == 63) wsum[w] = xinc;
        __syncthreads();
        if (w == 0 && lane < 8) {
            unsigned y  = wsum[lane];
            unsigned yy = y;
            #pragma unroll
            for (int d = 1; d < 8; d <<= 1) {
                unsigned t = (unsigned)__shfl_up((int)yy, d);
                if (lane >= d) yy += t;
            }
            wsum[lane] = yy - y;   // exclusive wave offset
        }
        __syncthreads();
        unsigned ex = wsum[w] + (xinc - s);   // exclusive prefix for i0
        if (i0 < NB) {
            loff[i0] = ex;
            cnt2off[blk * CNT_STRIDE + i0] = ex | (v0 << 16);
        }
        if (i1 < NB) {
            loff[i1] = ex + v0;
            cnt2off[blk * CNT_STRIDE + i1] = (ex + v0) | (v1 << 16);
        }
    }
    __syncthreads();

    // pass 2: LDS scatter into bucket-sorted order (loff doubles as cursor)
    for (int i = tid; i < ne; i += 512) {
        unsigned ent  = ent_sh[i];
        unsigned dst  = ent & 0xFFFFu;
        unsigned pos  = atomicAdd(&loff[dst >> 6], 1u);
        sort_sh[pos]  = (ent >> 16) | ((dst & 63u) << 16);   // src | dstlow<<16
    }
    __syncthreads();

    // coalesced private write-out
    for (int i = tid; i < ne; i += 512)
        edge_sorted[blk * SEG_STRIDE + i] = sort_sh[i];
}

// ---------------------------------------------------------------------------
// 2) fused: gather this bucket's edges from 256 private segments ->
//    counting-sort by dst-low (x8-padded segments, dummy srcs) ->
//    quarter-wave-per-node gather (8-deep) -> bf16 MFMA GEMM.
// ---------------------------------------------------------------------------
constexpr int A_STRIDE = 136;   // u16 units; 272B row stride (16B-divisible)

__global__ __launch_bounds__(512) void k_fused(
    const unsigned short* __restrict__ x_bf16,
    const unsigned short* __restrict__ B_packed,
    const float* __restrict__ b_msg, const float* __restrict__ b_self,
    const unsigned* __restrict__ cnt2off,
    const unsigned* __restrict__ edge_sorted,
    float* __restrict__ out)
{
    __shared__ __align__(16) unsigned short A_sh[64 * A_STRIDE];   // 17408 B
    __shared__ __align__(16) unsigned short B_sh[64 * A_STRIDE];   // 17408 B
    __shared__ unsigned short sorted_sh[BUCKET_CAP];               // 3584 B
    __shared__ unsigned cnt_sh[64];      // true counts by dst-low
    __shared__ unsigned poff_sh[64];     // padded exclusive offsets
    __shared__ unsigned woff_sh[64];     // scatter cursors

    int tid  = threadIdx.x;
    int w    = tid >> 6;       // wave 0..7
    int lane = tid & 63;
    int r0   = blockIdx.x * 64;

    // per-bin-block segment metadata for THIS bucket (threads 0..255 own seg j=tid)
    unsigned scnt = 0u;
    const unsigned* segp = nullptr;
    if (tid < 256) {
        unsigned meta = cnt2off[tid * CNT_STRIDE + blockIdx.x];
        segp = edge_sorted + tid * SEG_STRIDE + (meta & 0xFFFFu);
        scnt = meta >> 16;
    }

    if (tid < 64) cnt_sh[tid] = 0u;
    // stage A x-rows (k<64): 8x 16B chunks per row
    for (int idx = tid; idx < 64 * 8; idx += 512) {
        int row = idx >> 3;
        int c   = idx & 7;
        int g   = r0 + row;
        uint4 v = make_uint4(0u, 0u, 0u, 0u);
        if (g < N_NODES) v = *(const uint4*)&x_bf16[g * D + c * 8];
        *(uint4*)&A_sh[row * A_STRIDE + c * 8] = v;
    }
    // stage B: 16x 16B chunks per row
    for (int idx = tid; idx < 64 * 16; idx += 512) {
        int n = idx >> 4;
        int c = idx & 15;
        uint4 v = *(const uint4*)&B_packed[n * 128 + c * 8];
        *(uint4*)&B_sh[n * A_STRIDE + c * 8] = v;
    }
    // prefill sorted list with dummy srcs (covers padding gaps)
    for (int i = tid; i < BUCKET_CAP; i += 512)
        sorted_sh[i] = (unsigned short)ZERO_ROW;
    __syncthreads();

    // count by dst-low (read private segments; L2-resident)
    for (unsigned u = 0; u < scnt; ++u)
        atomicAdd(&cnt_sh[segp[u] >> 16], 1u);
    __syncthreads();

    // padded (x8) exclusive scan (wave 0)
    if (tid < 64) {
        unsigned c  = cnt_sh[tid];
        unsigned pc = (c + 7u) & ~7u;
        unsigned xsum = pc;
        #pragma unroll
        for (int s = 1; s < 64; s <<= 1) {
            unsigned v = (unsigned)__shfl_up((int)xsum, s);
            if (lane >= s) xsum += v;
        }
        poff_sh[tid] = xsum - pc;
        woff_sh[tid] = xsum - pc;
    }
    __syncthreads();

    // scatter srcs into dst-ordered padded segments (re-read segments)
    for (unsigned u = 0; u < scnt; ++u) {
        unsigned e = segp[u];
        unsigned slot = atomicAdd(&woff_sh[e >> 16], 1u);
        sorted_sh[slot] = (unsigned short)(e & 0xFFFFu);
    }
    __syncthreads();

    // --- gather: quarter-wave per node; wave w covers nodes w*8..w*8+7
    //     in 2 passes of 4 parallel nodes. 8 loads in flight per quarter-wave.
    int Q = lane >> 4;
    int f = lane & 15;

    #pragma unroll
    for (int pass = 0; pass < 2; ++pass) {
        int lrow = w * 8 + pass * 4 + Q;
        unsigned s0 = poff_sh[lrow];
        unsigned dc = cnt_sh[lrow];
        unsigned pc = (dc + 7u) & ~7u;

        float a0 = 0.f, a1 = 0.f, a2 = 0.f, a3 = 0.f;
        for (unsigned j = 0; j < pc; j += 8u) {
            ushort4 rv[8];
            #pragma unroll
            for (int u = 0; u < 8; ++u) {
                unsigned src = (unsigned)sorted_sh[s0 + j + u];
                rv[u] = *(const ushort4*)&x_bf16[(src << 6) + 4u * (unsigned)f];
            }
            #pragma unroll
            for (int u = 0; u < 8; ++u) {
                a0 += bf2f(rv[u].x); a1 += bf2f(rv[u].y);
                a2 += bf2f(rv[u].z); a3 += bf2f(rv[u].w);
            }
        }
        float inv = dc ? 1.0f / (float)dc : 0.0f;
        uint2 p;
        p.x = pack2(a0 * inv, a1 * inv);
        p.y = pack2(a2 * inv, a3 * inv);
        *(uint2*)&A_sh[lrow * A_STRIDE + 64 + 4 * f] = p;
    }
    __syncthreads();

    // MFMA: wave w -> m-rows 16*(w&3), n-tiles {2*(w>>2), 2*(w>>2)+1}
    int wm   = w & 3;
    int ng   = (w >> 2) * 2;
    int quad = lane >> 4;
    int l15  = lane & 15;

    f32x4 accr[2] = {{0.f,0.f,0.f,0.f},{0.f,0.f,0.f,0.f}};

    #pragma unroll
    for (int k0 = 0; k0 < 128; k0 += 32) {
        short8 a = *(const short8*)&A_sh[(16 * wm + l15) * A_STRIDE + k0 + quad * 8];
        #pragma unroll
        for (int t = 0; t < 2; ++t) {
            short8 b = *(const short8*)&B_sh[(16 * (ng + t) + l15) * A_STRIDE + k0 + quad * 8];
            accr[t] = __builtin_amdgcn_mfma_f32_16x16x32_bf16(a, b, accr[t], 0, 0, 0);
        }
    }

    #pragma unroll
    for (int t = 0; t < 2; ++t) {
        int col = (ng + t) * 16 + l15;
        float bs = b_self[col];
        float bm = b_msg[col];
        #pragma unroll
        for (int r = 0; r < 4; ++r) {
            int lrow = 16 * wm + quad * 4 + r;
            int grow = r0 + lrow;
            if (grow < N_NODES) {
                float vv = accr[t][r] + bs + (cnt_sh[lrow] > 0u ? bm : 0.0f);
                out[grow * D + col] = vv;
            }
        }
    }
}

// ---------------------------------------------------------------------------
extern "C" void kernel_launch(void* const* d_in, const int* in_sizes, int n_in,
                              void* d_out, int out_size, void* d_ws, size_t ws_size,
                              hipStream_t stream) {
    const float* x      = (const float*)d_in[0];
    const int*   edges  = (const int*)  d_in[1];
    const float* W_msg  = (const float*)d_in[2];
    const float* b_msg  = (const float*)d_in[3];
    const float* W_self = (const float*)d_in[4];
    const float* b_self = (const float*)d_in[5];
    float*       out    = (float*)d_out;

    // workspace layout (bytes), total ~10.4 MB. No memset needed.
    char* ws = (char*)d_ws;
    unsigned short* B_packed    = (unsigned short*)(ws + 0);         // 16384 B
    unsigned*       cnt2off     = (unsigned*)(ws + 16384);           // 256*784*4 = 802816 B
    unsigned*       edge_sorted = (unsigned*)(ws + 819200);          // 256*3136*4 = 3211264 B
    unsigned short* x_bf16      = (unsigned short*)(ws + 4030464);   // 50001 rows x 128 B

    k_bin_place<<<BIN_BLOCKS, 512, 0, stream>>>(x, x_bf16, W_msg, W_self,
                                                B_packed, edges, cnt2off, edge_sorted);
    k_fused<<<NB, 512, 0, stream>>>(x_bf16, B_packed, b_msg, b_self,
                                    cnt2off, edge_sorted, out);
}